// Round 11
// baseline (263.118 us; speedup 1.0000x reference)
//
#include <hip/hip_runtime.h>
#include <hip/hip_fp16.h>
#include <math.h>

#define N_NODES 50000
#define N_EDGES 1600000
#define DIM 128
#define HEADS 8
#define NEG_SLOPE 0.2f
#define BN_EPS 1e-5f

typedef _Float16 f16x8 __attribute__((ext_vector_type(8)));
typedef float f32x4 __attribute__((ext_vector_type(4)));

// ---------------------------------------------------------------------------
// CSR build: bucket b = dst>>7 (391 buckets of 128 nodes).
// R11 insight: build kernels are PER-BLOCK LDS-PIPE-PATH bound (R10 PMC +
// R3/R9 wall-time accounting: blocks all concurrent -> wall = one block's
// LDS op chain). Fix = halve per-block LDS ops, double block count:
//   binA: 4096-edge chunks (391 blocks), co-packed with 391 lin blocks.
//   binB: 128-node buckets (391 standalone 512-thread blocks).
// Same atomic-free meta scheme as R9 (proven correct).
// ---------------------------------------------------------------------------
#define NBUCK 391          // ceil(50000/128) buckets of 128 nodes
#define BSEGCAP 4864       // bucket mean 4092 + ~12 sigma
#define CHUNK 4096         // binA chunk edges (halved)
#define NB_A ((N_EDGES + CHUNK - 1) / CHUNK)   // 391
#define LIN_NB ((N_NODES + 127) / 128)          // 391 (8 waves x 16 nodes)
#define P1_NB (NB_A + LIN_NB)                   // 782

struct BinAShm {
    int hist[NBUCK], excl[NBUCK], cnt2[NBUCK];  // 4.7 KB
    int sc[512];                                // 2 KB
    unsigned int buf[CHUNK];                    // 16 KB
};
struct LinShm { __half wh[16384]; };            // 32 KB

// ---------------------------------------------------------------------------
// lin: xl = x @ W via MFMA 16x16x32 f16, W swizzled fp32->fp16 in LDS;
// fused per-head attention dots, logits pre-scaled by 1/ln2 (exp2 later).
// ---------------------------------------------------------------------------
__device__ __forceinline__ void lin_block(
        int linb, const float* __restrict__ x, const float* __restrict__ W,
        const float* __restrict__ att_s, const float* __restrict__ att_d,
        __half* __restrict__ xlh, float* __restrict__ a_src,
        float* __restrict__ a_dst, __half* wh) {
    const int t = threadIdx.x;
    // stage W: frag g=nt*4+kt: lane holds B[k=kt*32+q*8+j][n=nt*16+(lane&15)]
    for (int v = t; v < 2048; v += 512) {
        const int g = v >> 6, lane = v & 63;
        const int nt = g >> 2, kt = g & 3;
        const int q = lane >> 4, n = lane & 15;
        #pragma unroll
        for (int j = 0; j < 8; ++j)
            wh[(size_t)(g * 64 + lane) * 8 + j] =
                __float2half(W[(kt * 32 + q * 8 + j) * DIM + nt * 16 + n]);
    }
    __syncthreads();

    const int wave = t >> 6;
    const int lane = t & 63;
    const int q = lane >> 4, n = lane & 15;
    const int nb = (linb * 8 + wave) * 16;

    const int rowA = min(nb + n, N_NODES - 1);
    const float* xr = x + (size_t)rowA * DIM;
    f16x8 a[4];
    #pragma unroll
    for (int kt = 0; kt < 4; ++kt) {
        const float4 p0 = *(const float4*)(xr + kt * 32 + q * 8);
        const float4 p1 = *(const float4*)(xr + kt * 32 + q * 8 + 4);
        a[kt][0] = (_Float16)p0.x; a[kt][1] = (_Float16)p0.y;
        a[kt][2] = (_Float16)p0.z; a[kt][3] = (_Float16)p0.w;
        a[kt][4] = (_Float16)p1.x; a[kt][5] = (_Float16)p1.y;
        a[kt][6] = (_Float16)p1.z; a[kt][7] = (_Float16)p1.w;
    }

    f32x4 acc[8];
    #pragma unroll
    for (int nt = 0; nt < 8; ++nt) acc[nt] = (f32x4){0.f, 0.f, 0.f, 0.f};

    const f16x8* wb = (const f16x8*)wh;
    #pragma unroll
    for (int nt = 0; nt < 8; ++nt) {
        #pragma unroll
        for (int kt = 0; kt < 4; ++kt) {
            const f16x8 b = wb[(nt * 4 + kt) * 64 + lane];
            acc[nt] = __builtin_amdgcn_mfma_f32_16x16x32_f16(a[kt], b, acc[nt], 0, 0, 0);
        }
    }

    const int r0 = nb + q * 4;
    #pragma unroll
    for (int nt = 0; nt < 8; ++nt) {
        const float as = att_s[nt * 16 + n];
        const float ad = att_d[nt * 16 + n];
        #pragma unroll
        for (int r = 0; r < 4; ++r) {
            const int row = r0 + r;
            const float v = acc[nt][r];
            float s = v * as;
            float d = v * ad;
            #pragma unroll
            for (int off = 8; off; off >>= 1) {
                s += __shfl_xor(s, off, 16);
                d += __shfl_xor(d, off, 16);
            }
            if (row < N_NODES) {
                xlh[(size_t)row * DIM + nt * 16 + n] = __float2half(v);
                if (n == 0) {
                    a_src[row * HEADS + nt] = s * 1.44269504f;
                    a_dst[row * HEADS + nt] = d * 1.44269504f;
                }
            }
        }
    }
}

// ---------------------------------------------------------------------------
// K1: blocks [0, NB_A) = binA (4096-edge chunks); [NB_A, P1_NB) = all lin.
// ---------------------------------------------------------------------------
__global__ __launch_bounds__(512) void k_phase1(
        const float* __restrict__ x, const float* __restrict__ W,
        const float* __restrict__ att_s, const float* __restrict__ att_d,
        const int* __restrict__ ei, unsigned int* __restrict__ meta,
        unsigned int* __restrict__ pairs, __half* __restrict__ xlh,
        float* __restrict__ a_src, float* __restrict__ a_dst) {
    __shared__ union { BinAShm a; LinShm l; } sh;
    const int t = threadIdx.x;

    if (blockIdx.x < NB_A) {
        // ----- binA: LDS counting sort of one 4096-edge chunk by bucket -----
        const int blk = blockIdx.x;
        const int base = blk * CHUNK;
        const int cnt = min(CHUNK, N_EDGES - base);   // multiple of 4

        for (int j = t; j < NBUCK; j += 512) { sh.a.hist[j] = 0; sh.a.cnt2[j] = 0; }
        __syncthreads();
        for (int i = t * 4; i < cnt; i += 2048) {
            const int4 dv = *(const int4*)(ei + N_EDGES + base + i);
            atomicAdd(&sh.a.hist[dv.x >> 7], 1);
            atomicAdd(&sh.a.hist[dv.y >> 7], 1);
            atomicAdd(&sh.a.hist[dv.z >> 7], 1);
            atomicAdd(&sh.a.hist[dv.w >> 7], 1);
        }
        __syncthreads();
        sh.a.sc[t] = (t < NBUCK) ? sh.a.hist[t] : 0;
        __syncthreads();
        for (int d = 1; d < 512; d <<= 1) {
            int xo = 0;
            if (t >= d) xo = sh.a.sc[t - d];
            __syncthreads();
            sh.a.sc[t] += xo;
            __syncthreads();
        }
        if (t < NBUCK) {
            const int ex = sh.a.sc[t] - sh.a.hist[t];
            sh.a.excl[t] = ex;
            // publish {len, off} for this (chunk, bucket): no global atomics
            meta[(size_t)blk * NBUCK + t] =
                (unsigned int)sh.a.hist[t] | ((unsigned int)ex << 16);
        }
        __syncthreads();
        for (int i = t * 4; i < cnt; i += 2048) {
            const int4 sv = *(const int4*)(ei + base + i);
            const int4 dv = *(const int4*)(ei + N_EDGES + base + i);
            const int ss[4] = {sv.x, sv.y, sv.z, sv.w};
            const int dd[4] = {dv.x, dv.y, dv.z, dv.w};
            #pragma unroll
            for (int k = 0; k < 4; ++k) {
                const int b = dd[k] >> 7;
                const int r = atomicAdd(&sh.a.cnt2[b], 1);
                sh.a.buf[sh.a.excl[b] + r] = (unsigned int)ss[k]
                    | ((unsigned int)(dd[k] & 127) << 16);
            }
        }
        __syncthreads();
        // coalesced flush into this block's OWN region
        for (int i = t * 4; i < cnt; i += 2048)
            *(int4*)(pairs + base + i) = *(const int4*)(sh.a.buf + i);
    } else {
        lin_block(blockIdx.x - NB_A, x, W, att_s, att_d, xlh, a_src, a_dst, sh.l.wh);
    }
}

// ---------------------------------------------------------------------------
// K2 (binB): one 512-thread block per 128-node bucket. Two coalesced
// wave-per-run walks (pass1 histogram, pass2 scatter into LDS staging),
// then coalesced flush to csr segment + nrange. ~8K LDS ops per block
// (half of R9's), 391 blocks spread the LDS work across more CUs.
// Block 0 zeroes BN accumulators.
// ---------------------------------------------------------------------------
__global__ __launch_bounds__(512) void k_binB(
        const unsigned int* __restrict__ pairs, const unsigned int* __restrict__ meta,
        unsigned short* __restrict__ csr, int2* __restrict__ nrange,
        float* __restrict__ gsums) {
    __shared__ int la[NB_A], ea[NB_A];          // 391 each (3.1 KB)
    __shared__ int hist[128], excl[128], cnt2[128], sc[128];
    __shared__ unsigned short out[BSEGCAP];     // 9.5 KB
    const int t = threadIdx.x;
    const int b = blockIdx.x;
    if (b == 0 && t < 256) gsums[t] = 0.f;

    if (t < NB_A) {
        const unsigned int m = meta[(size_t)t * NBUCK + b];
        la[t] = (int)(m & 0xFFFF);
        ea[t] = (int)(m >> 16);
    }
    if (t < 128) { hist[t] = 0; cnt2[t] = 0; }
    __syncthreads();

    const int wave = t >> 6, lane = t & 63;

    // pass 1: per-node histogram via coalesced run walk
    for (int r = wave; r < NB_A; r += 8) {
        const int len = la[r];
        const unsigned int* src = pairs + (size_t)r * CHUNK + ea[r];
        for (int j = lane; j < len; j += 64)
            atomicAdd(&hist[(src[j] >> 16) & 127], 1);
    }
    __syncthreads();
    if (t < 128) sc[t] = hist[t];
    __syncthreads();
    for (int d = 1; d < 128; d <<= 1) {
        int xo = 0;
        if (t < 128 && t >= d) xo = sc[t - d];
        __syncthreads();
        if (t < 128) sc[t] += xo;
        __syncthreads();
    }
    if (t < 128) {
        excl[t] = sc[t] - hist[t];
        const int node = (b << 7) + t;
        if (node < N_NODES) {
            int2 rg;
            rg.x = b * BSEGCAP + excl[t];
            rg.y = rg.x + hist[t];
            nrange[node] = rg;
        }
    }
    __syncthreads();
    const int cnt = min(sc[127], BSEGCAP);

    // pass 2: scatter into node-sorted LDS staging (src runs L2-hot)
    for (int r = wave; r < NB_A; r += 8) {
        const int len = la[r];
        const unsigned int* src = pairs + (size_t)r * CHUNK + ea[r];
        for (int j = lane; j < len; j += 64) {
            const unsigned int u = src[j];
            const int dl = (u >> 16) & 127;
            const int p = atomicAdd(&cnt2[dl], 1);
            const int pos = excl[dl] + p;
            if (pos < BSEGCAP) out[pos] = (unsigned short)(u & 0xFFFF);
        }
    }
    __syncthreads();
    // coalesced flush into this bucket's private csr window
    for (int i = t; i < cnt; i += 512)
        csr[(size_t)b * BSEGCAP + i] = out[i];
}

// ---------------------------------------------------------------------------
// K3 v9 (unchanged, proven 61 µs): fused softmax + aggregation. One node per
// wave, 4 edge-groups x 16 lanes, lane covers 8 channels via one f16x8
// gather; 16-edge main loop. Logits pre-scaled by 1/ln2 -> bare exp2f.
// ---------------------------------------------------------------------------
#define AGG_NB (N_NODES / 4)   // 12500

__global__ void k_aggr9(const int2* __restrict__ nrange,
                        const unsigned short* __restrict__ csr,
                        const float* __restrict__ a_src, const float* __restrict__ a_dst,
                        const __half* __restrict__ xlh, float* __restrict__ y) {
    const int d = blockIdx.x * 4 + (threadIdx.x >> 6);
    const int lane = threadIdx.x & 63;
    const int g = lane >> 4;        // edge sub-group 0..3
    const int cl = lane & 15;       // channel slot: channels [cl*8, cl*8+8)
    const int h = cl >> 1;          // head owning this slot (OUT_C=16)
    const int2 rg = nrange[d];
    const int lo = rg.x, hi = rg.y;
    const float ad = a_dst[d * HEADS + h];

    float acc[8];
    #pragma unroll
    for (int k = 0; k < 8; ++k) acc[k] = 0.f;
    float dsum = 0.f;

    int i = lo;
    for (; i + 16 <= hi; i += 16) {
        const int s0 = csr[i + g];
        const int s1 = csr[i + 4 + g];
        const int s2 = csr[i + 8 + g];
        const int s3 = csr[i + 12 + g];
        const float as0 = a_src[s0 * HEADS + h];
        const float as1 = a_src[s1 * HEADS + h];
        const float as2 = a_src[s2 * HEADS + h];
        const float as3 = a_src[s3 * HEADS + h];
        const f16x8 x0 = *(const f16x8*)(xlh + (size_t)s0 * DIM + cl * 8);
        const f16x8 x1 = *(const f16x8*)(xlh + (size_t)s1 * DIM + cl * 8);
        const f16x8 x2 = *(const f16x8*)(xlh + (size_t)s2 * DIM + cl * 8);
        const f16x8 x3 = *(const f16x8*)(xlh + (size_t)s3 * DIM + cl * 8);
        const float e0 = as0 + ad;
        const float e1 = as1 + ad;
        const float e2 = as2 + ad;
        const float e3 = as3 + ad;
        const float w0 = exp2f(fmaxf(e0, NEG_SLOPE * e0));
        const float w1 = exp2f(fmaxf(e1, NEG_SLOPE * e1));
        const float w2 = exp2f(fmaxf(e2, NEG_SLOPE * e2));
        const float w3 = exp2f(fmaxf(e3, NEG_SLOPE * e3));
        dsum += (w0 + w1) + (w2 + w3);
        #pragma unroll
        for (int k = 0; k < 8; ++k) acc[k] = fmaf(w0, (float)x0[k], acc[k]);
        #pragma unroll
        for (int k = 0; k < 8; ++k) acc[k] = fmaf(w1, (float)x1[k], acc[k]);
        #pragma unroll
        for (int k = 0; k < 8; ++k) acc[k] = fmaf(w2, (float)x2[k], acc[k]);
        #pragma unroll
        for (int k = 0; k < 8; ++k) acc[k] = fmaf(w3, (float)x3[k], acc[k]);
    }
    for (; i + 8 <= hi; i += 8) {
        const int s0 = csr[i + g];
        const int s1 = csr[i + 4 + g];
        const float as0 = a_src[s0 * HEADS + h];
        const float as1 = a_src[s1 * HEADS + h];
        const f16x8 x0 = *(const f16x8*)(xlh + (size_t)s0 * DIM + cl * 8);
        const f16x8 x1 = *(const f16x8*)(xlh + (size_t)s1 * DIM + cl * 8);
        const float e0 = as0 + ad;
        const float e1 = as1 + ad;
        const float w0 = exp2f(fmaxf(e0, NEG_SLOPE * e0));
        const float w1 = exp2f(fmaxf(e1, NEG_SLOPE * e1));
        dsum += w0 + w1;
        #pragma unroll
        for (int k = 0; k < 8; ++k) acc[k] = fmaf(w0, (float)x0[k], acc[k]);
        #pragma unroll
        for (int k = 0; k < 8; ++k) acc[k] = fmaf(w1, (float)x1[k], acc[k]);
    }
    for (; i < hi; i += 4) {
        const int idx = i + g;
        const int sv = csr[min(idx, hi - 1)];
        const float e = a_src[sv * HEADS + h] + ad;
        const f16x8 xv = *(const f16x8*)(xlh + (size_t)sv * DIM + cl * 8);
        float w = exp2f(fmaxf(e, NEG_SLOPE * e));
        if (idx >= hi) w = 0.f;
        dsum += w;
        #pragma unroll
        for (int k = 0; k < 8; ++k) acc[k] = fmaf(w, (float)xv[k], acc[k]);
    }
    #pragma unroll
    for (int k = 0; k < 8; ++k) {
        acc[k] += __shfl_xor(acc[k], 16);
        acc[k] += __shfl_xor(acc[k], 32);
    }
    dsum += __shfl_xor(dsum, 16);
    dsum += __shfl_xor(dsum, 32);
    const float inv = 1.f / (dsum + 1e-16f);
    float2 o;
    o.x = acc[2 * g] * inv;
    o.y = acc[2 * g + 1] * inv;
    *(float2*)(y + (size_t)d * DIM + cl * 8 + g * 2) = o;
}

// ---------------------------------------------------------------------------
// BN stats over h = y + bias (512 blocks x 128 threads)
// ---------------------------------------------------------------------------
__global__ void k_stats(const float* __restrict__ y, const float* __restrict__ bias,
                        float* __restrict__ gsums) {
    const int c = threadIdx.x;
    const float b = bias[c];
    float s = 0.f, ss = 0.f;
    for (int n = blockIdx.x; n < N_NODES; n += gridDim.x) {
        const float h = y[n * DIM + c] + b;
        s += h;
        ss += h * h;
    }
    atomicAdd(&gsums[c], s);
    atomicAdd(&gsums[DIM + c], ss);
}

// ---------------------------------------------------------------------------
// K4: y = x + relu((y + bias - mean) * rsqrt(var+eps) * gamma + beta)
// ---------------------------------------------------------------------------
__global__ void k_final(float* __restrict__ y, const float* __restrict__ x,
                        const float* __restrict__ sums, const float* __restrict__ sumsq,
                        const float* __restrict__ gamma, const float* __restrict__ beta,
                        const float* __restrict__ bias) {
    const int q = blockIdx.x * blockDim.x + threadIdx.x;
    const int cq = q & (DIM / 4 - 1);
    const float4 sm = ((const float4*)sums)[cq];
    const float4 sq = ((const float4*)sumsq)[cq];
    const float4 gm = ((const float4*)gamma)[cq];
    const float4 bt = ((const float4*)beta)[cq];
    const float4 bs = ((const float4*)bias)[cq];
    float4 v = ((const float4*)y)[q];
    const float4 xv = ((const float4*)x)[q];
    const float inv_n = 1.f / (float)N_NODES;
#define BNC(c) { const float mean = sm.c * inv_n;                         \
                 const float var = sq.c * inv_n - mean * mean;            \
                 const float sc = rsqrtf(var + BN_EPS) * gm.c;            \
                 const float sh = bt.c + (bs.c - mean) * sc;              \
                 v.c = xv.c + fmaxf(v.c * sc + sh, 0.f); }
    BNC(x) BNC(y) BNC(z) BNC(w)
#undef BNC
    ((float4*)y)[q] = v;
}

extern "C" void kernel_launch(void* const* d_in, const int* in_sizes, int n_in,
                              void* d_out, int out_size, void* d_ws, size_t ws_size,
                              hipStream_t stream) {
    const float* x     = (const float*)d_in[0];
    const int*   ei    = (const int*)  d_in[1];
    const float* W     = (const float*)d_in[2];
    const float* att_s = (const float*)d_in[3];
    const float* att_d = (const float*)d_in[4];
    const float* bias  = (const float*)d_in[5];
    const float* gamma = (const float*)d_in[6];
    const float* beta  = (const float*)d_in[7];
    float* y = (float*)d_out;

    // workspace layout (~26 MiB)
    __half* xlh  = (__half*)d_ws;                          // 12.8 MB
    float* a_src = (float*)(xlh + (size_t)N_NODES * DIM);  // 1.6 MB
    float* a_dst = a_src + (size_t)N_NODES * HEADS;        // 1.6 MB
    float* sums  = a_dst + (size_t)N_NODES * HEADS;        // 512 B
    float* sumsq = sums  + DIM;                            // 512 B
    int2*  nrange = (int2*)(sumsq + DIM);                  // 400 KB
    unsigned int* meta  = (unsigned int*)(nrange + N_NODES);   // 391*391 u32 (611 KB)
    unsigned int* pairs = meta + (size_t)NB_A * NBUCK;         // 391*4096 u32 (6.4 MB)
    unsigned short* csr = (unsigned short*)(pairs + (size_t)NB_A * CHUNK); // 3.8 MB

    k_phase1<<<P1_NB, 512, 0, stream>>>(x, W, att_s, att_d, ei, meta, pairs,
                                        xlh, a_src, a_dst);
    k_binB<<<NBUCK, 512, 0, stream>>>(pairs, meta, csr, nrange, sums);
    k_aggr9<<<AGG_NB, 256, 0, stream>>>(nrange, csr, a_src, a_dst, xlh, y);
    k_stats<<<512, DIM, 0, stream>>>(y, bias, sums);
    k_final<<<(size_t)N_NODES * DIM / 4 / 256, 256, 0, stream>>>(y, x, sums, sumsq,
                                                                 gamma, beta, bias);
}

// Round 12
// 226.463 us; speedup vs baseline: 1.1619x; 1.1619x over previous
//
#include <hip/hip_runtime.h>
#include <hip/hip_fp16.h>
#include <math.h>

#define N_NODES 50000
#define N_EDGES 1600000
#define DIM 128
#define HEADS 8
#define NEG_SLOPE 0.2f
#define BN_EPS 1e-5f

typedef _Float16 f16x8 __attribute__((ext_vector_type(8)));
typedef float f32x4 __attribute__((ext_vector_type(4)));

// ---------------------------------------------------------------------------
// R12 = exact R3 pipeline (best, 229 us) + two changes:
//  (1) k_aggr9 split into two half-grid launches so phase1/binB/final
//      surface in the rocprof top-5 (they have never been measured).
//  (2) k_stats accumulates into 8 replicated gsum banks (blockIdx&7) to cut
//      512-deep same-address atomic serialization; k_red reduces the banks.
// ---------------------------------------------------------------------------
#define NBUCK 196
#define SEGCAP 12288
#define CHUNK 8192
#define NB_A ((N_EDGES + CHUNK - 1) / CHUNK)   // 196
#define LIN_NB ((N_NODES + 127) / 128)          // 391 (8 waves x 16 nodes)
#define FUSED_NB (NB_A + LIN_NB)                // 587

struct BinAShm {
    int hist[NBUCK], excl[NBUCK], gbase[NBUCK], cnt2[NBUCK];
    int sc[256];
    unsigned int buf[CHUNK];                // 32 KB
};
struct LinShm { __half wh[16384]; };        // 32 KB

__global__ __launch_bounds__(512) void k_linbinA(
        const float* __restrict__ x, const float* __restrict__ W,
        const float* __restrict__ att_s, const float* __restrict__ att_d,
        const int* __restrict__ ei, int* __restrict__ bcur,
        unsigned int* __restrict__ pairs, __half* __restrict__ xlh,
        float* __restrict__ a_src, float* __restrict__ a_dst) {
    __shared__ union { BinAShm a; LinShm l; } sh;
    const int t = threadIdx.x;

    if (blockIdx.x < NB_A) {
        // ----- binA -----
        const int base = blockIdx.x * CHUNK;
        const int cnt = min(CHUNK, N_EDGES - base);   // multiple of 4

        for (int j = t; j < NBUCK; j += 512) { sh.a.hist[j] = 0; sh.a.cnt2[j] = 0; }
        __syncthreads();
        for (int i = t * 4; i < cnt; i += 2048) {
            const int4 dv = *(const int4*)(ei + N_EDGES + base + i);
            atomicAdd(&sh.a.hist[dv.x >> 8], 1);
            atomicAdd(&sh.a.hist[dv.y >> 8], 1);
            atomicAdd(&sh.a.hist[dv.z >> 8], 1);
            atomicAdd(&sh.a.hist[dv.w >> 8], 1);
        }
        __syncthreads();
        if (t < 256) sh.a.sc[t] = (t < NBUCK) ? sh.a.hist[t] : 0;
        __syncthreads();
        for (int d = 1; d < 256; d <<= 1) {
            int xo = 0;
            if (t < 256 && t >= d) xo = sh.a.sc[t - d];
            __syncthreads();
            if (t < 256) sh.a.sc[t] += xo;
            __syncthreads();
        }
        if (t < NBUCK) {
            sh.a.excl[t] = sh.a.sc[t] - sh.a.hist[t];
            sh.a.gbase[t] = t * SEGCAP + atomicAdd(&bcur[t], sh.a.hist[t]);
        }
        __syncthreads();
        for (int i = t * 4; i < cnt; i += 2048) {
            const int4 sv = *(const int4*)(ei + base + i);
            const int4 dv = *(const int4*)(ei + N_EDGES + base + i);
            const int ss[4] = {sv.x, sv.y, sv.z, sv.w};
            const int dd[4] = {dv.x, dv.y, dv.z, dv.w};
            #pragma unroll
            for (int k = 0; k < 4; ++k) {
                const int b = dd[k] >> 8;
                const int r = atomicAdd(&sh.a.cnt2[b], 1);
                sh.a.buf[sh.a.excl[b] + r] = (unsigned int)ss[k]
                    | ((unsigned int)(dd[k] & 255) << 16) | ((unsigned int)b << 24);
            }
        }
        __syncthreads();
        for (int i = t; i < cnt; i += 512) {
            const unsigned int u = sh.a.buf[i];
            const int b = u >> 24;
            pairs[sh.a.gbase[b] + (i - sh.a.excl[b])] = u & 0xFFFFFF;
        }
    } else {
        // ----- lin -----
        for (int v = t; v < 2048; v += 512) {
            const int g = v >> 6, lane = v & 63;
            const int nt = g >> 2, kt = g & 3;
            const int q = lane >> 4, n = lane & 15;
            #pragma unroll
            for (int j = 0; j < 8; ++j)
                sh.l.wh[(size_t)(g * 64 + lane) * 8 + j] =
                    __float2half(W[(kt * 32 + q * 8 + j) * DIM + nt * 16 + n]);
        }
        __syncthreads();

        const int wave = t >> 6;
        const int lane = t & 63;
        const int q = lane >> 4, n = lane & 15;
        const int nb = ((blockIdx.x - NB_A) * 8 + wave) * 16;

        const int rowA = min(nb + n, N_NODES - 1);
        const float* xr = x + (size_t)rowA * DIM;
        f16x8 a[4];
        #pragma unroll
        for (int kt = 0; kt < 4; ++kt) {
            const float4 p0 = *(const float4*)(xr + kt * 32 + q * 8);
            const float4 p1 = *(const float4*)(xr + kt * 32 + q * 8 + 4);
            a[kt][0] = (_Float16)p0.x; a[kt][1] = (_Float16)p0.y;
            a[kt][2] = (_Float16)p0.z; a[kt][3] = (_Float16)p0.w;
            a[kt][4] = (_Float16)p1.x; a[kt][5] = (_Float16)p1.y;
            a[kt][6] = (_Float16)p1.z; a[kt][7] = (_Float16)p1.w;
        }

        f32x4 acc[8];
        #pragma unroll
        for (int nt = 0; nt < 8; ++nt) acc[nt] = (f32x4){0.f, 0.f, 0.f, 0.f};

        const f16x8* wb = (const f16x8*)sh.l.wh;
        #pragma unroll
        for (int nt = 0; nt < 8; ++nt) {
            #pragma unroll
            for (int kt = 0; kt < 4; ++kt) {
                const f16x8 b = wb[(nt * 4 + kt) * 64 + lane];
                acc[nt] = __builtin_amdgcn_mfma_f32_16x16x32_f16(a[kt], b, acc[nt], 0, 0, 0);
            }
        }

        const int r0 = nb + q * 4;
        #pragma unroll
        for (int nt = 0; nt < 8; ++nt) {
            const float as = att_s[nt * 16 + n];
            const float ad = att_d[nt * 16 + n];
            #pragma unroll
            for (int r = 0; r < 4; ++r) {
                const int row = r0 + r;
                const float v = acc[nt][r];
                float s = v * as;
                float d = v * ad;
                #pragma unroll
                for (int off = 8; off; off >>= 1) {
                    s += __shfl_xor(s, off, 16);
                    d += __shfl_xor(d, off, 16);
                }
                if (row < N_NODES) {
                    xlh[(size_t)row * DIM + nt * 16 + n] = __float2half(v);
                    if (n == 0) {
                        a_src[row * HEADS + nt] = s * 1.44269504f;
                        a_dst[row * HEADS + nt] = d * 1.44269504f;
                    }
                }
            }
        }
    }
}

// ---------------------------------------------------------------------------
// binB (R3-exact): one block per bucket; LDS counting sort by dst&255.
// Node segments padded to EVEN csr indices. Block 0 zeroes the 8 replicated
// gsum banks (2048 floats).
// ---------------------------------------------------------------------------
__global__ __launch_bounds__(1024) void k_binB(const unsigned int* __restrict__ pairs,
                                               const int* __restrict__ bcur,
                                               unsigned short* __restrict__ csr,
                                               int2* __restrict__ nrange,
                                               float* __restrict__ grep) {
    __shared__ int hist[256], eh[256], excl[256], cnt2[256];
    __shared__ int plen;
    __shared__ unsigned short out[SEGCAP];  // 24 KB
    const int t = threadIdx.x;
    const int b = blockIdx.x;
    if (b == 0) { for (int j = t; j < 2048; j += 1024) grep[j] = 0.f; }
    const int lo = b * SEGCAP;              // u32 index into pairs
    const int cnt = bcur[b];

    if (t < 256) { hist[t] = 0; cnt2[t] = 0; }
    __syncthreads();
    for (int i = t; i < cnt; i += 1024)
        atomicAdd(&hist[pairs[lo + i] >> 16], 1);
    __syncthreads();
    if (t < 256) { eh[t] = (hist[t] + 1) & ~1; excl[t] = eh[t]; }
    __syncthreads();
    for (int d = 1; d < 256; d <<= 1) {
        int xo = 0;
        if (t < 256 && t >= d) xo = excl[t - d];
        __syncthreads();
        if (t < 256) excl[t] += xo;
        __syncthreads();
    }
    if (t < 256) excl[t] -= eh[t];          // exclusive padded starts (even)
    if (t == 255) plen = excl[255] + eh[255];
    __syncthreads();
    for (int i = t; i < cnt; i += 1024) {
        const unsigned int u = pairs[lo + i];
        const int dl = u >> 16;
        const int r = atomicAdd(&cnt2[dl], 1);
        out[excl[dl] + r] = (unsigned short)(u & 0xFFFF);
    }
    __syncthreads();
    const int pl = plen;                    // <= cnt + 256 <= SEGCAP
    for (int i = t; i < pl; i += 1024)
        csr[2 * lo + i] = out[i];           // pad gaps: garbage, never read
    if (t < 256) {
        const int node = (b << 8) + t;
        if (node < N_NODES) {
            int2 rg;
            rg.x = 2 * lo + excl[t];
            rg.y = rg.x + hist[t];
            nrange[node] = rg;
        }
    }
}

// ---------------------------------------------------------------------------
// K3 v9 (proven): fused softmax + aggregation. Takes a node-base so the
// grid can be split into two launches (diagnostic: surfaces other kernels
// in rocprof top-5).
// ---------------------------------------------------------------------------
#define AGG_HALF_NB (N_NODES / 8)   // 6250 blocks per half

__global__ void k_aggr9(const int2* __restrict__ nrange,
                        const unsigned short* __restrict__ csr,
                        const float* __restrict__ a_src, const float* __restrict__ a_dst,
                        const __half* __restrict__ xlh, float* __restrict__ y,
                        int nbase) {
    const int d = nbase + blockIdx.x * 4 + (threadIdx.x >> 6);
    const int lane = threadIdx.x & 63;
    const int g = lane >> 4;        // edge sub-group 0..3
    const int cl = lane & 15;       // channel slot: channels [cl*8, cl*8+8)
    const int h = cl >> 1;          // head owning this slot (OUT_C=16)
    const int2 rg = nrange[d];
    const int lo = rg.x, hi = rg.y;
    const float ad = a_dst[d * HEADS + h];

    float acc[8];
    #pragma unroll
    for (int k = 0; k < 8; ++k) acc[k] = 0.f;
    float dsum = 0.f;

    int i = lo;
    for (; i + 16 <= hi; i += 16) {
        const int s0 = csr[i + g];
        const int s1 = csr[i + 4 + g];
        const int s2 = csr[i + 8 + g];
        const int s3 = csr[i + 12 + g];
        const float as0 = a_src[s0 * HEADS + h];
        const float as1 = a_src[s1 * HEADS + h];
        const float as2 = a_src[s2 * HEADS + h];
        const float as3 = a_src[s3 * HEADS + h];
        const f16x8 x0 = *(const f16x8*)(xlh + (size_t)s0 * DIM + cl * 8);
        const f16x8 x1 = *(const f16x8*)(xlh + (size_t)s1 * DIM + cl * 8);
        const f16x8 x2 = *(const f16x8*)(xlh + (size_t)s2 * DIM + cl * 8);
        const f16x8 x3 = *(const f16x8*)(xlh + (size_t)s3 * DIM + cl * 8);
        const float e0 = as0 + ad;
        const float e1 = as1 + ad;
        const float e2 = as2 + ad;
        const float e3 = as3 + ad;
        const float w0 = exp2f(fmaxf(e0, NEG_SLOPE * e0));
        const float w1 = exp2f(fmaxf(e1, NEG_SLOPE * e1));
        const float w2 = exp2f(fmaxf(e2, NEG_SLOPE * e2));
        const float w3 = exp2f(fmaxf(e3, NEG_SLOPE * e3));
        dsum += (w0 + w1) + (w2 + w3);
        #pragma unroll
        for (int k = 0; k < 8; ++k) acc[k] = fmaf(w0, (float)x0[k], acc[k]);
        #pragma unroll
        for (int k = 0; k < 8; ++k) acc[k] = fmaf(w1, (float)x1[k], acc[k]);
        #pragma unroll
        for (int k = 0; k < 8; ++k) acc[k] = fmaf(w2, (float)x2[k], acc[k]);
        #pragma unroll
        for (int k = 0; k < 8; ++k) acc[k] = fmaf(w3, (float)x3[k], acc[k]);
    }
    for (; i + 8 <= hi; i += 8) {
        const int s0 = csr[i + g];
        const int s1 = csr[i + 4 + g];
        const float as0 = a_src[s0 * HEADS + h];
        const float as1 = a_src[s1 * HEADS + h];
        const f16x8 x0 = *(const f16x8*)(xlh + (size_t)s0 * DIM + cl * 8);
        const f16x8 x1 = *(const f16x8*)(xlh + (size_t)s1 * DIM + cl * 8);
        const float e0 = as0 + ad;
        const float e1 = as1 + ad;
        const float w0 = exp2f(fmaxf(e0, NEG_SLOPE * e0));
        const float w1 = exp2f(fmaxf(e1, NEG_SLOPE * e1));
        dsum += w0 + w1;
        #pragma unroll
        for (int k = 0; k < 8; ++k) acc[k] = fmaf(w0, (float)x0[k], acc[k]);
        #pragma unroll
        for (int k = 0; k < 8; ++k) acc[k] = fmaf(w1, (float)x1[k], acc[k]);
    }
    for (; i < hi; i += 4) {
        const int idx = i + g;
        const int sv = csr[min(idx, hi - 1)];
        const float e = a_src[sv * HEADS + h] + ad;
        const f16x8 xv = *(const f16x8*)(xlh + (size_t)sv * DIM + cl * 8);
        float w = exp2f(fmaxf(e, NEG_SLOPE * e));
        if (idx >= hi) w = 0.f;
        dsum += w;
        #pragma unroll
        for (int k = 0; k < 8; ++k) acc[k] = fmaf(w, (float)xv[k], acc[k]);
    }
    #pragma unroll
    for (int k = 0; k < 8; ++k) {
        acc[k] += __shfl_xor(acc[k], 16);
        acc[k] += __shfl_xor(acc[k], 32);
    }
    dsum += __shfl_xor(dsum, 16);
    dsum += __shfl_xor(dsum, 32);
    const float inv = 1.f / (dsum + 1e-16f);
    float2 o;
    o.x = acc[2 * g] * inv;
    o.y = acc[2 * g + 1] * inv;
    *(float2*)(y + (size_t)d * DIM + cl * 8 + g * 2) = o;
}

// ---------------------------------------------------------------------------
// BN stats over h = y + bias: 8 replicated banks (blockIdx&7) cut the
// same-address atomic depth 512 -> 64. Bank r: grep[r*256 + c] = sum,
// grep[r*256 + 128 + c] = sumsq.
// ---------------------------------------------------------------------------
__global__ void k_stats(const float* __restrict__ y, const float* __restrict__ bias,
                        float* __restrict__ grep) {
    const int c = threadIdx.x;
    const float b = bias[c];
    float* bank = grep + (blockIdx.x & 7) * 256;
    float s = 0.f, ss = 0.f;
    for (int n = blockIdx.x; n < N_NODES; n += gridDim.x) {
        const float h = y[n * DIM + c] + b;
        s += h;
        ss += h * h;
    }
    atomicAdd(&bank[c], s);
    atomicAdd(&bank[DIM + c], ss);
}

// single-block reduce of the 8 banks -> gred[0:128]=sums, gred[128:256]=sumsq
__global__ void k_red(const float* __restrict__ grep, float* __restrict__ gred) {
    const int j = threadIdx.x;   // 0..255
    float v = 0.f;
    #pragma unroll
    for (int r = 0; r < 8; ++r) v += grep[r * 256 + j];
    gred[j] = v;
}

// ---------------------------------------------------------------------------
// K4: y = x + relu((y + bias - mean) * rsqrt(var+eps) * gamma + beta)
// ---------------------------------------------------------------------------
__global__ void k_final(float* __restrict__ y, const float* __restrict__ x,
                        const float* __restrict__ sums, const float* __restrict__ sumsq,
                        const float* __restrict__ gamma, const float* __restrict__ beta,
                        const float* __restrict__ bias) {
    const int q = blockIdx.x * blockDim.x + threadIdx.x;
    const int cq = q & (DIM / 4 - 1);
    const float4 sm = ((const float4*)sums)[cq];
    const float4 sq = ((const float4*)sumsq)[cq];
    const float4 gm = ((const float4*)gamma)[cq];
    const float4 bt = ((const float4*)beta)[cq];
    const float4 bs = ((const float4*)bias)[cq];
    float4 v = ((const float4*)y)[q];
    const float4 xv = ((const float4*)x)[q];
    const float inv_n = 1.f / (float)N_NODES;
#define BNC(c) { const float mean = sm.c * inv_n;                         \
                 const float var = sq.c * inv_n - mean * mean;            \
                 const float sc = rsqrtf(var + BN_EPS) * gm.c;            \
                 const float sh = bt.c + (bs.c - mean) * sc;              \
                 v.c = xv.c + fmaxf(v.c * sc + sh, 0.f); }
    BNC(x) BNC(y) BNC(z) BNC(w)
#undef BNC
    ((float4*)y)[q] = v;
}

extern "C" void kernel_launch(void* const* d_in, const int* in_sizes, int n_in,
                              void* d_out, int out_size, void* d_ws, size_t ws_size,
                              hipStream_t stream) {
    const float* x     = (const float*)d_in[0];
    const int*   ei    = (const int*)  d_in[1];
    const float* W     = (const float*)d_in[2];
    const float* att_s = (const float*)d_in[3];
    const float* att_d = (const float*)d_in[4];
    const float* bias  = (const float*)d_in[5];
    const float* gamma = (const float*)d_in[6];
    const float* beta  = (const float*)d_in[7];
    float* y = (float*)d_out;

    // workspace layout
    __half* xlh  = (__half*)d_ws;                          // 12.8 MB
    float* a_src = (float*)(xlh + (size_t)N_NODES * DIM);  // 1.6 MB
    float* a_dst = a_src + (size_t)N_NODES * HEADS;        // 1.6 MB
    float* gred  = a_dst + (size_t)N_NODES * HEADS;        // 256 f (reduced stats)
    float* grep  = gred + 256;                             // 2048 f (8 banks)
    int*   bcur  = (int*)(grep + 2048);                    // 256 i
    int2*  nrange = (int2*)(bcur + 256);                   // 50,000 int2
    unsigned int* pairs = (unsigned int*)(nrange + N_NODES); // 196*12288 u32 (9.6 MB)
    unsigned short* csr = (unsigned short*)pairs;          // aliases pairs (in-place)

    hipMemsetAsync(bcur, 0, 256 * sizeof(int), stream);
    k_linbinA<<<FUSED_NB, 512, 0, stream>>>(x, W, att_s, att_d, ei, bcur, pairs,
                                            xlh, a_src, a_dst);
    k_binB<<<NBUCK, 1024, 0, stream>>>(pairs, bcur, csr, nrange, grep);
    k_aggr9<<<AGG_HALF_NB, 256, 0, stream>>>(nrange, csr, a_src, a_dst, xlh, y, 0);
    k_aggr9<<<AGG_HALF_NB, 256, 0, stream>>>(nrange, csr, a_src, a_dst, xlh, y,
                                             N_NODES / 2);
    k_stats<<<512, DIM, 0, stream>>>(y, bias, grep);
    k_red<<<1, 256, 0, stream>>>(grep, gred);
    k_final<<<(size_t)N_NODES * DIM / 4 / 256, 256, 0, stream>>>(y, x, gred,
                                                                 gred + DIM,
                                                                 gamma, beta, bias);
}

// Round 13
// 222.532 us; speedup vs baseline: 1.1824x; 1.0177x over previous
//
#include <hip/hip_runtime.h>
#include <hip/hip_fp16.h>
#include <math.h>

#define N_NODES 50000
#define N_EDGES 1600000
#define DIM 128
#define HEADS 8
#define NEG_SLOPE 0.2f
#define BN_EPS 1e-5f

typedef _Float16 f16x8 __attribute__((ext_vector_type(8)));
typedef float f32x4 __attribute__((ext_vector_type(4)));

// ---------------------------------------------------------------------------
// R13 = R12 structure consolidated: single aggr launch, k_red folded into
// k_final (per-block 8-bank LDS reduce). 6 dispatches total.
// Known budget (R12 PMC): harness ws-poison fill 42us (untouchable, in-stream)
// + linbinA <42 + binB <42 + aggr ~62 (compulsory traffic) + stats ~8 +
// final ~10 + gaps.
// ---------------------------------------------------------------------------
#define NBUCK 196
#define SEGCAP 12288
#define CHUNK 8192
#define NB_A ((N_EDGES + CHUNK - 1) / CHUNK)   // 196
#define LIN_NB ((N_NODES + 127) / 128)          // 391 (8 waves x 16 nodes)
#define FUSED_NB (NB_A + LIN_NB)                // 587

struct BinAShm {
    int hist[NBUCK], excl[NBUCK], gbase[NBUCK], cnt2[NBUCK];
    int sc[256];
    unsigned int buf[CHUNK];                // 32 KB
};
struct LinShm { __half wh[16384]; };        // 32 KB

__global__ __launch_bounds__(512) void k_linbinA(
        const float* __restrict__ x, const float* __restrict__ W,
        const float* __restrict__ att_s, const float* __restrict__ att_d,
        const int* __restrict__ ei, int* __restrict__ bcur,
        unsigned int* __restrict__ pairs, __half* __restrict__ xlh,
        float* __restrict__ a_src, float* __restrict__ a_dst) {
    __shared__ union { BinAShm a; LinShm l; } sh;
    const int t = threadIdx.x;

    if (blockIdx.x < NB_A) {
        // ----- binA -----
        const int base = blockIdx.x * CHUNK;
        const int cnt = min(CHUNK, N_EDGES - base);   // multiple of 4

        for (int j = t; j < NBUCK; j += 512) { sh.a.hist[j] = 0; sh.a.cnt2[j] = 0; }
        __syncthreads();
        for (int i = t * 4; i < cnt; i += 2048) {
            const int4 dv = *(const int4*)(ei + N_EDGES + base + i);
            atomicAdd(&sh.a.hist[dv.x >> 8], 1);
            atomicAdd(&sh.a.hist[dv.y >> 8], 1);
            atomicAdd(&sh.a.hist[dv.z >> 8], 1);
            atomicAdd(&sh.a.hist[dv.w >> 8], 1);
        }
        __syncthreads();
        if (t < 256) sh.a.sc[t] = (t < NBUCK) ? sh.a.hist[t] : 0;
        __syncthreads();
        for (int d = 1; d < 256; d <<= 1) {
            int xo = 0;
            if (t < 256 && t >= d) xo = sh.a.sc[t - d];
            __syncthreads();
            if (t < 256) sh.a.sc[t] += xo;
            __syncthreads();
        }
        if (t < NBUCK) {
            sh.a.excl[t] = sh.a.sc[t] - sh.a.hist[t];
            sh.a.gbase[t] = t * SEGCAP + atomicAdd(&bcur[t], sh.a.hist[t]);
        }
        __syncthreads();
        for (int i = t * 4; i < cnt; i += 2048) {
            const int4 sv = *(const int4*)(ei + base + i);
            const int4 dv = *(const int4*)(ei + N_EDGES + base + i);
            const int ss[4] = {sv.x, sv.y, sv.z, sv.w};
            const int dd[4] = {dv.x, dv.y, dv.z, dv.w};
            #pragma unroll
            for (int k = 0; k < 4; ++k) {
                const int b = dd[k] >> 8;
                const int r = atomicAdd(&sh.a.cnt2[b], 1);
                sh.a.buf[sh.a.excl[b] + r] = (unsigned int)ss[k]
                    | ((unsigned int)(dd[k] & 255) << 16) | ((unsigned int)b << 24);
            }
        }
        __syncthreads();
        for (int i = t; i < cnt; i += 512) {
            const unsigned int u = sh.a.buf[i];
            const int b = u >> 24;
            pairs[sh.a.gbase[b] + (i - sh.a.excl[b])] = u & 0xFFFFFF;
        }
    } else {
        // ----- lin -----
        for (int v = t; v < 2048; v += 512) {
            const int g = v >> 6, lane = v & 63;
            const int nt = g >> 2, kt = g & 3;
            const int q = lane >> 4, n = lane & 15;
            #pragma unroll
            for (int j = 0; j < 8; ++j)
                sh.l.wh[(size_t)(g * 64 + lane) * 8 + j] =
                    __float2half(W[(kt * 32 + q * 8 + j) * DIM + nt * 16 + n]);
        }
        __syncthreads();

        const int wave = t >> 6;
        const int lane = t & 63;
        const int q = lane >> 4, n = lane & 15;
        const int nb = ((blockIdx.x - NB_A) * 8 + wave) * 16;

        const int rowA = min(nb + n, N_NODES - 1);
        const float* xr = x + (size_t)rowA * DIM;
        f16x8 a[4];
        #pragma unroll
        for (int kt = 0; kt < 4; ++kt) {
            const float4 p0 = *(const float4*)(xr + kt * 32 + q * 8);
            const float4 p1 = *(const float4*)(xr + kt * 32 + q * 8 + 4);
            a[kt][0] = (_Float16)p0.x; a[kt][1] = (_Float16)p0.y;
            a[kt][2] = (_Float16)p0.z; a[kt][3] = (_Float16)p0.w;
            a[kt][4] = (_Float16)p1.x; a[kt][5] = (_Float16)p1.y;
            a[kt][6] = (_Float16)p1.z; a[kt][7] = (_Float16)p1.w;
        }

        f32x4 acc[8];
        #pragma unroll
        for (int nt = 0; nt < 8; ++nt) acc[nt] = (f32x4){0.f, 0.f, 0.f, 0.f};

        const f16x8* wb = (const f16x8*)sh.l.wh;
        #pragma unroll
        for (int nt = 0; nt < 8; ++nt) {
            #pragma unroll
            for (int kt = 0; kt < 4; ++kt) {
                const f16x8 b = wb[(nt * 4 + kt) * 64 + lane];
                acc[nt] = __builtin_amdgcn_mfma_f32_16x16x32_f16(a[kt], b, acc[nt], 0, 0, 0);
            }
        }

        const int r0 = nb + q * 4;
        #pragma unroll
        for (int nt = 0; nt < 8; ++nt) {
            const float as = att_s[nt * 16 + n];
            const float ad = att_d[nt * 16 + n];
            #pragma unroll
            for (int r = 0; r < 4; ++r) {
                const int row = r0 + r;
                const float v = acc[nt][r];
                float s = v * as;
                float d = v * ad;
                #pragma unroll
                for (int off = 8; off; off >>= 1) {
                    s += __shfl_xor(s, off, 16);
                    d += __shfl_xor(d, off, 16);
                }
                if (row < N_NODES) {
                    xlh[(size_t)row * DIM + nt * 16 + n] = __float2half(v);
                    if (n == 0) {
                        a_src[row * HEADS + nt] = s * 1.44269504f;
                        a_dst[row * HEADS + nt] = d * 1.44269504f;
                    }
                }
            }
        }
    }
}

// ---------------------------------------------------------------------------
// binB (R3-exact): one block per bucket; LDS counting sort by dst&255.
// Node segments padded to EVEN csr indices. Block 0 zeroes the 8 replicated
// gsum banks (2048 floats).
// ---------------------------------------------------------------------------
__global__ __launch_bounds__(1024) void k_binB(const unsigned int* __restrict__ pairs,
                                               const int* __restrict__ bcur,
                                               unsigned short* __restrict__ csr,
                                               int2* __restrict__ nrange,
                                               float* __restrict__ grep) {
    __shared__ int hist[256], eh[256], excl[256], cnt2[256];
    __shared__ int plen;
    __shared__ unsigned short out[SEGCAP];  // 24 KB
    const int t = threadIdx.x;
    const int b = blockIdx.x;
    if (b == 0) { for (int j = t; j < 2048; j += 1024) grep[j] = 0.f; }
    const int lo = b * SEGCAP;              // u32 index into pairs
    const int cnt = bcur[b];

    if (t < 256) { hist[t] = 0; cnt2[t] = 0; }
    __syncthreads();
    for (int i = t; i < cnt; i += 1024)
        atomicAdd(&hist[pairs[lo + i] >> 16], 1);
    __syncthreads();
    if (t < 256) { eh[t] = (hist[t] + 1) & ~1; excl[t] = eh[t]; }
    __syncthreads();
    for (int d = 1; d < 256; d <<= 1) {
        int xo = 0;
        if (t < 256 && t >= d) xo = excl[t - d];
        __syncthreads();
        if (t < 256) excl[t] += xo;
        __syncthreads();
    }
    if (t < 256) excl[t] -= eh[t];          // exclusive padded starts (even)
    if (t == 255) plen = excl[255] + eh[255];
    __syncthreads();
    for (int i = t; i < cnt; i += 1024) {
        const unsigned int u = pairs[lo + i];
        const int dl = u >> 16;
        const int r = atomicAdd(&cnt2[dl], 1);
        out[excl[dl] + r] = (unsigned short)(u & 0xFFFF);
    }
    __syncthreads();
    const int pl = plen;                    // <= cnt + 256 <= SEGCAP
    for (int i = t; i < pl; i += 1024)
        csr[2 * lo + i] = out[i];           // pad gaps: garbage, never read
    if (t < 256) {
        const int node = (b << 8) + t;
        if (node < N_NODES) {
            int2 rg;
            rg.x = 2 * lo + excl[t];
            rg.y = rg.x + hist[t];
            nrange[node] = rg;
        }
    }
}

// ---------------------------------------------------------------------------
// K3 v9 (proven 61 µs): fused softmax + aggregation. One node per wave,
// 4 edge-groups x 16 lanes, lane covers 8 channels via one f16x8 gather;
// 16-edge main loop. Logits pre-scaled by 1/ln2 -> bare exp2f.
// ---------------------------------------------------------------------------
#define AGG_NB (N_NODES / 4)   // 12500

__global__ void k_aggr9(const int2* __restrict__ nrange,
                        const unsigned short* __restrict__ csr,
                        const float* __restrict__ a_src, const float* __restrict__ a_dst,
                        const __half* __restrict__ xlh, float* __restrict__ y) {
    const int d = blockIdx.x * 4 + (threadIdx.x >> 6);
    const int lane = threadIdx.x & 63;
    const int g = lane >> 4;        // edge sub-group 0..3
    const int cl = lane & 15;       // channel slot: channels [cl*8, cl*8+8)
    const int h = cl >> 1;          // head owning this slot (OUT_C=16)
    const int2 rg = nrange[d];
    const int lo = rg.x, hi = rg.y;
    const float ad = a_dst[d * HEADS + h];

    float acc[8];
    #pragma unroll
    for (int k = 0; k < 8; ++k) acc[k] = 0.f;
    float dsum = 0.f;

    int i = lo;
    for (; i + 16 <= hi; i += 16) {
        const int s0 = csr[i + g];
        const int s1 = csr[i + 4 + g];
        const int s2 = csr[i + 8 + g];
        const int s3 = csr[i + 12 + g];
        const float as0 = a_src[s0 * HEADS + h];
        const float as1 = a_src[s1 * HEADS + h];
        const float as2 = a_src[s2 * HEADS + h];
        const float as3 = a_src[s3 * HEADS + h];
        const f16x8 x0 = *(const f16x8*)(xlh + (size_t)s0 * DIM + cl * 8);
        const f16x8 x1 = *(const f16x8*)(xlh + (size_t)s1 * DIM + cl * 8);
        const f16x8 x2 = *(const f16x8*)(xlh + (size_t)s2 * DIM + cl * 8);
        const f16x8 x3 = *(const f16x8*)(xlh + (size_t)s3 * DIM + cl * 8);
        const float e0 = as0 + ad;
        const float e1 = as1 + ad;
        const float e2 = as2 + ad;
        const float e3 = as3 + ad;
        const float w0 = exp2f(fmaxf(e0, NEG_SLOPE * e0));
        const float w1 = exp2f(fmaxf(e1, NEG_SLOPE * e1));
        const float w2 = exp2f(fmaxf(e2, NEG_SLOPE * e2));
        const float w3 = exp2f(fmaxf(e3, NEG_SLOPE * e3));
        dsum += (w0 + w1) + (w2 + w3);
        #pragma unroll
        for (int k = 0; k < 8; ++k) acc[k] = fmaf(w0, (float)x0[k], acc[k]);
        #pragma unroll
        for (int k = 0; k < 8; ++k) acc[k] = fmaf(w1, (float)x1[k], acc[k]);
        #pragma unroll
        for (int k = 0; k < 8; ++k) acc[k] = fmaf(w2, (float)x2[k], acc[k]);
        #pragma unroll
        for (int k = 0; k < 8; ++k) acc[k] = fmaf(w3, (float)x3[k], acc[k]);
    }
    for (; i + 8 <= hi; i += 8) {
        const int s0 = csr[i + g];
        const int s1 = csr[i + 4 + g];
        const float as0 = a_src[s0 * HEADS + h];
        const float as1 = a_src[s1 * HEADS + h];
        const f16x8 x0 = *(const f16x8*)(xlh + (size_t)s0 * DIM + cl * 8);
        const f16x8 x1 = *(const f16x8*)(xlh + (size_t)s1 * DIM + cl * 8);
        const float e0 = as0 + ad;
        const float e1 = as1 + ad;
        const float w0 = exp2f(fmaxf(e0, NEG_SLOPE * e0));
        const float w1 = exp2f(fmaxf(e1, NEG_SLOPE * e1));
        dsum += w0 + w1;
        #pragma unroll
        for (int k = 0; k < 8; ++k) acc[k] = fmaf(w0, (float)x0[k], acc[k]);
        #pragma unroll
        for (int k = 0; k < 8; ++k) acc[k] = fmaf(w1, (float)x1[k], acc[k]);
    }
    for (; i < hi; i += 4) {
        const int idx = i + g;
        const int sv = csr[min(idx, hi - 1)];
        const float e = a_src[sv * HEADS + h] + ad;
        const f16x8 xv = *(const f16x8*)(xlh + (size_t)sv * DIM + cl * 8);
        float w = exp2f(fmaxf(e, NEG_SLOPE * e));
        if (idx >= hi) w = 0.f;
        dsum += w;
        #pragma unroll
        for (int k = 0; k < 8; ++k) acc[k] = fmaf(w, (float)xv[k], acc[k]);
    }
    #pragma unroll
    for (int k = 0; k < 8; ++k) {
        acc[k] += __shfl_xor(acc[k], 16);
        acc[k] += __shfl_xor(acc[k], 32);
    }
    dsum += __shfl_xor(dsum, 16);
    dsum += __shfl_xor(dsum, 32);
    const float inv = 1.f / (dsum + 1e-16f);
    float2 o;
    o.x = acc[2 * g] * inv;
    o.y = acc[2 * g + 1] * inv;
    *(float2*)(y + (size_t)d * DIM + cl * 8 + g * 2) = o;
}

// ---------------------------------------------------------------------------
// BN stats over h = y + bias: 8 replicated banks (blockIdx&7) cut the
// same-address atomic depth 512 -> 64. Bank r: grep[r*256 + c] = sum,
// grep[r*256 + 128 + c] = sumsq.
// ---------------------------------------------------------------------------
__global__ void k_stats(const float* __restrict__ y, const float* __restrict__ bias,
                        float* __restrict__ grep) {
    const int c = threadIdx.x;
    const float b = bias[c];
    float* bank = grep + (blockIdx.x & 7) * 256;
    float s = 0.f, ss = 0.f;
    for (int n = blockIdx.x; n < N_NODES; n += gridDim.x) {
        const float h = y[n * DIM + c] + b;
        s += h;
        ss += h * h;
    }
    atomicAdd(&bank[c], s);
    atomicAdd(&bank[DIM + c], ss);
}

// ---------------------------------------------------------------------------
// K4: y = x + relu((y + bias - mean) * rsqrt(var+eps) * gamma + beta).
// Inline 8-bank reduce: each block folds grep's 8 banks into LDS once
// (8 KB of L2-hot loads), then all 256 threads read their channels from LDS.
// ---------------------------------------------------------------------------
__global__ __launch_bounds__(256) void k_final(
        float* __restrict__ y, const float* __restrict__ x,
        const float* __restrict__ grep,
        const float* __restrict__ gamma, const float* __restrict__ beta,
        const float* __restrict__ bias) {
    __shared__ float sred[256];             // [0:128]=sums, [128:256]=sumsq
    const int t = threadIdx.x;
    {
        float v = 0.f;
        #pragma unroll
        for (int r = 0; r < 8; ++r) v += grep[r * 256 + t];
        sred[t] = v;
    }
    __syncthreads();

    const int q = blockIdx.x * blockDim.x + t;
    const int cq = q & (DIM / 4 - 1);
    const float4 sm = ((const float4*)sred)[cq];
    const float4 sq = ((const float4*)(sred + DIM))[cq];
    const float4 gm = ((const float4*)gamma)[cq];
    const float4 bt = ((const float4*)beta)[cq];
    const float4 bs = ((const float4*)bias)[cq];
    float4 v = ((const float4*)y)[q];
    const float4 xv = ((const float4*)x)[q];
    const float inv_n = 1.f / (float)N_NODES;
#define BNC(c) { const float mean = sm.c * inv_n;                         \
                 const float var = sq.c * inv_n - mean * mean;            \
                 const float sc = rsqrtf(var + BN_EPS) * gm.c;            \
                 const float sh = bt.c + (bs.c - mean) * sc;              \
                 v.c = xv.c + fmaxf(v.c * sc + sh, 0.f); }
    BNC(x) BNC(y) BNC(z) BNC(w)
#undef BNC
    ((float4*)y)[q] = v;
}

extern "C" void kernel_launch(void* const* d_in, const int* in_sizes, int n_in,
                              void* d_out, int out_size, void* d_ws, size_t ws_size,
                              hipStream_t stream) {
    const float* x     = (const float*)d_in[0];
    const int*   ei    = (const int*)  d_in[1];
    const float* W     = (const float*)d_in[2];
    const float* att_s = (const float*)d_in[3];
    const float* att_d = (const float*)d_in[4];
    const float* bias  = (const float*)d_in[5];
    const float* gamma = (const float*)d_in[6];
    const float* beta  = (const float*)d_in[7];
    float* y = (float*)d_out;

    // workspace layout
    __half* xlh  = (__half*)d_ws;                          // 12.8 MB
    float* a_src = (float*)(xlh + (size_t)N_NODES * DIM);  // 1.6 MB
    float* a_dst = a_src + (size_t)N_NODES * HEADS;        // 1.6 MB
    float* grep  = a_dst + (size_t)N_NODES * HEADS;        // 2048 f (8 banks)
    int*   bcur  = (int*)(grep + 2048);                    // 256 i
    int2*  nrange = (int2*)(bcur + 256);                   // 50,000 int2
    unsigned int* pairs = (unsigned int*)(nrange + N_NODES); // 196*12288 u32 (9.6 MB)
    unsigned short* csr = (unsigned short*)pairs;          // aliases pairs (in-place)

    hipMemsetAsync(bcur, 0, 256 * sizeof(int), stream);
    k_linbinA<<<FUSED_NB, 512, 0, stream>>>(x, W, att_s, att_d, ei, bcur, pairs,
                                            xlh, a_src, a_dst);
    k_binB<<<NBUCK, 1024, 0, stream>>>(pairs, bcur, csr, nrange, grep);
    k_aggr9<<<AGG_NB, 256, 0, stream>>>(nrange, csr, a_src, a_dst, xlh, y);
    k_stats<<<512, DIM, 0, stream>>>(y, bias, grep);
    k_final<<<(size_t)N_NODES * DIM / 4 / 256, 256, 0, stream>>>(y, x, grep,
                                                                 gamma, beta, bias);
}